// Round 3
// baseline (617.372 us; speedup 1.0000x reference)
//
#include <hip/hip_runtime.h>
#include <hip/hip_bf16.h>

// Problem constants (B=8, S=4096, D=1024, H=16, hd=64). All I/O is FLOAT32.
#define TOKENS   32768
#define DMODEL   1024
#define THREE_D  3072

using u16 = unsigned short;
typedef __attribute__((ext_vector_type(8))) short short8;  // 8 bf16 = 4 VGPRs
typedef __attribute__((ext_vector_type(4))) float f32x4;

__device__ __forceinline__ float bf2f(u16 u) {
  union { unsigned int i; float f; } v; v.i = ((unsigned int)u) << 16; return v.f;
}
__device__ __forceinline__ u16 f2bf(float f) {
  __hip_bfloat16 h = __float2bfloat16(f);   // RNE
  return *reinterpret_cast<u16*>(&h);
}

// async global->LDS, 16B per lane; LDS dest = wave-uniform base + lane*16
__device__ __forceinline__ void gload_lds16(const u16* g, u16* l) {
  __builtin_amdgcn_global_load_lds((const __attribute__((address_space(1))) void*)g,
                                   (__attribute__((address_space(3))) void*)l,
                                   16, 0, 0);
}

// ---------------------------------------------------------------------------
// f32 -> bf16 elementwise convert (n divisible by 1024)
// ---------------------------------------------------------------------------
__global__ __launch_bounds__(256) void convert_f32_bf16(const float* __restrict__ in,
                                                        u16* __restrict__ out, long n) {
  long i = ((long)blockIdx.x * 256 + threadIdx.x) * 4;
  if (i >= n) return;
  float4 v = *reinterpret_cast<const float4*>(in + i);
  ushort4 o;
  o.x = f2bf(v.x); o.y = f2bf(v.y); o.z = f2bf(v.z); o.w = f2bf(v.w);
  *reinterpret_cast<ushort4*>(out + i) = o;
}

// ---------------------------------------------------------------------------
// f32 in (R x C) -> bf16 out (C x R) transpose+convert. R, C multiples of 32.
// ---------------------------------------------------------------------------
__global__ __launch_bounds__(256) void transpose_convert(const float* __restrict__ in,
                                                         u16* __restrict__ out,
                                                         int R, int C) {
  __shared__ u16 tile[32][33];
  const int bc = blockIdx.x * 32;
  const int br = blockIdx.y * 32;
  const int tx = threadIdx.x & 31;
  const int ty = threadIdx.x >> 5;
  #pragma unroll
  for (int i = 0; i < 32; i += 8)
    tile[ty + i][tx] = f2bf(in[(long)(br + ty + i) * C + bc + tx]);
  __syncthreads();
  #pragma unroll
  for (int i = 0; i < 32; i += 8)
    out[(long)(bc + ty + i) * R + br + tx] = tile[tx][ty + i];
}

// ---------------------------------------------------------------------------
// C(M,N) = A(M,K) @ BT(N,K)^T + bias(N).  A,BT bf16; bias f32; MFMA f32 acc.
// 256x256 tile, 8 waves (512 thr), BK=64.  SINGLE-BARRIER region schedule:
// each region = { barrier; lgkm(0); 16 MFMA (frags read LAST region); stage;
// ds_read frags for NEXT region; [VM4/VM0 at r3/r7-equiv]; }.  Fragment reads
// overlap the next region's... i.e., this region's MFMA cluster runs on the
// MFMA pipe while the LDS pipe serves the reads issued in the SAME region --
// the m196 interleave.  Reads overwrite the just-consumed a/b registers
// (operands latch at MFMA issue -> no WAR), so no extra VGPRs.
//
// Quadrant order per K-tile: (QR,QC) = (0,0),(1,0),(1,1),(0,1).
// Region list (main loop, 2 tiles, BUF0=t&1=0, BUF1=1):
//  r1: MM(0,0)b0  rdA(b0,QR1)            stA0[t+1]  -
//  r2: MM(1,0)b0  rdB(b0,QC1)            stB0[t+2]  -
//  r3: MM(1,1)b0  rdA(b0,QR0)            stA1[t+2]  VM4 (retires thru r1)
//  r4: MM(0,1)b0  rdA(b1,QR0)+rdB(b1,QC0) stB1[t+2]  -
//  r5: MM(0,0)b1  rdA(b1,QR1)            stA0[t+2]  -
//  r6: MM(1,0)b1  rdB(b1,QC1)            stB0[t+3]  -
//  r7: MM(1,1)b1  rdA(b1,QR0)            stA1[t+3]  VM4 (retires thru r5)
//  r8: MM(0,1)b1  rdA(b0,QR0)+rdB(b0,QC0) stB1[t+3]  -
// Hazard lattice (verified): every stage's target region was last ds_read
// >=1 barrier earlier; every read of staged data is preceded by a vmcnt
// retiring that stage BEFORE an intervening barrier (cross-wave visibility).
// Same-region stage/read LDS regions are disjoint in all 8 regions.
// vmcnt never drains to 0 in the main loop (once in the peel).
//
// XOR chunk swizzle (0 bank conflicts, measured): staging lane L covers row
// base+(L>>3), phys 16B chunk (L&7), loading GLOBAL chunk (L&7)^(L>>3);
// reads fetch global chunk c of row r at phys c^(r&7).
//
// A read through column remap: logical col c -> row*a_stride + (c>>6)*a_grp
// + (c&63).  Identity: a_stride=K, a_grp=64.  M%256==0, N%256==0,
// K%128==0 (NT even, >= 4).
// ---------------------------------------------------------------------------
#define BM 256
#define BN 256
#define BK 64

#define VM4 asm volatile("s_waitcnt vmcnt(4)" ::: "memory")
#define VM6 asm volatile("s_waitcnt vmcnt(6)" ::: "memory")
#define VM0 asm volatile("s_waitcnt vmcnt(0)" ::: "memory")
#define VMN ((void)0)
#define NOSTAGE ((void)0)

// stage one 128-row half (H) of A or B for K-tile T into buffer (T&1): 2 loads
#define STAGE_A(T, H)                                                          \
  { _Pragma("unroll") for (int j_ = 0; j_ < 2; j_++) {                         \
      const int lr_ = (H) * 128 + (wave * 2 + j_) * 8;                         \
      gload_lds16(A + (long)(bm + lr_ + sr) * a_stride + (long)(T) * a_grp + scol, \
                  &As[(T) & 1][lr_ * BK]);                                     \
  } }
#define STAGE_B(T, H)                                                          \
  { _Pragma("unroll") for (int j_ = 0; j_ < 2; j_++) {                         \
      const int lr_ = (H) * 128 + (wave * 2 + j_) * 8;                         \
      gload_lds16(BT + (long)(bn + lr_ + sr) * K + (T) * BK + scol,            \
                  &Bs[(T) & 1][lr_ * BK]);                                     \
  } }

// fragment reads (for the NEXT region's MFMA)
#define READ_A(BUF, QR)                                                        \
  { _Pragma("unroll") for (int mi = 0; mi < 2; mi++)                           \
      _Pragma("unroll") for (int kh = 0; kh < 2; kh++)                         \
        a[mi][kh] = *reinterpret_cast<const short8*>(                          \
            &As[BUF][((QR) * 128 + wrow + mi * 16 + lrow) * BK +               \
                     (((kh * 4 + quad) ^ xs) * 8)]); }
#define READ_B(BUF, QC)                                                        \
  { _Pragma("unroll") for (int ni = 0; ni < 4; ni++)                           \
      _Pragma("unroll") for (int kh = 0; kh < 2; kh++)                         \
        b[ni][kh] = *reinterpret_cast<const short8*>(                          \
            &Bs[BUF][((QC) * 128 + wcol + ni * 16 + lrow) * BK +               \
                     (((kh * 4 + quad) ^ xs) * 8)]); }

// one region: barrier; wait frags; MFMA quadrant (QR,QC); stage; next-reads; vmw
#define REGION(QR, QC, STAGE, READS, VMW)                                      \
  {                                                                            \
    __builtin_amdgcn_sched_barrier(0);                                         \
    __builtin_amdgcn_s_barrier();                                              \
    asm volatile("s_waitcnt lgkmcnt(0)" ::: "memory");                         \
    __builtin_amdgcn_sched_barrier(0);                                         \
    __builtin_amdgcn_s_setprio(1);                                             \
    _Pragma("unroll") for (int mi = 0; mi < 2; mi++)                           \
      _Pragma("unroll") for (int ni = 0; ni < 4; ni++) {                       \
        acc[QR][QC][mi][ni] = __builtin_amdgcn_mfma_f32_16x16x32_bf16(         \
            a[mi][0], b[ni][0], acc[QR][QC][mi][ni], 0, 0, 0);                 \
        acc[QR][QC][mi][ni] = __builtin_amdgcn_mfma_f32_16x16x32_bf16(         \
            a[mi][1], b[ni][1], acc[QR][QC][mi][ni], 0, 0, 0);                 \
      }                                                                        \
    __builtin_amdgcn_s_setprio(0);                                             \
    STAGE;                                                                     \
    READS;                                                                     \
    VMW;                                                                       \
  }

template <bool OUT_F32>
__global__ __launch_bounds__(512, 2) void gemm_bt_bias(
    const u16* __restrict__ A, const u16* __restrict__ BT,
    const float* __restrict__ bias, void* __restrict__ Cv,
    int M, int N, int K, long a_stride, int a_grp) {
  __shared__ alignas(16) u16 As[2][BM * BK];  // 64 KB
  __shared__ alignas(16) u16 Bs[2][BN * BK];  // 64 KB
  (void)M;

  // XCD-aware bijective swizzle (gridDim.x % 8 == 0 for our shapes)
  const int cpx = gridDim.x >> 3;
  const int wg  = ((int)blockIdx.x & 7) * cpx + ((int)blockIdx.x >> 3);
  const int tiles_n = N / BN;
  const int bm = (wg / tiles_n) * BM;
  const int bn = (wg % tiles_n) * BN;

  const int tid  = threadIdx.x;
  const int wave = tid >> 6;           // 0..7
  const int lane = tid & 63;
  const int wrow = (wave & 3) * 32;    // row slice within a 128-row quadrant
  const int wcol = (wave >> 2) * 64;   // col slice within a 128-col quadrant
  const int lrow = lane & 15;
  const int quad = lane >> 4;
  const int xs   = lrow & 7;

  // staging lane decomposition
  const int sr     = lane >> 3;              // row within 8-row group
  const int schunk = (lane & 7) ^ sr;        // GLOBAL 16B chunk this lane loads
  const int scol   = schunk * 8;

  const int NT = K / BK;   // even, >= 4

  f32x4 acc[2][2][2][4];
  #pragma unroll
  for (int i = 0; i < 2; i++)
    #pragma unroll
    for (int j = 0; j < 2; j++)
      #pragma unroll
      for (int m = 0; m < 2; m++)
        #pragma unroll
        for (int n = 0; n < 4; n++) acc[i][j][m][n] = (f32x4){0.f, 0.f, 0.f, 0.f};

  // prologue: tile0 fully (8 loads) + tile1's B0,A1,B1 (6 loads = the
  // {r6-,r7-,r8-} steady-state equivalents).  VM6 retires tile0; barrier makes
  // that visible to all waves; then pre-read tile0's (QR0,QC0) fragments.
  STAGE_A(0, 0); STAGE_B(0, 0); STAGE_A(0, 1); STAGE_B(0, 1);
  STAGE_B(1, 0); STAGE_A(1, 1); STAGE_B(1, 1);
  VM6;
  __builtin_amdgcn_s_barrier();

  short8 a[2][2];
  short8 b[4][2];
  READ_A(0, 0);
  READ_B(0, 0);

  #pragma unroll 1
  for (int t = 0; t + 3 < NT; t += 2) {
    REGION(0, 0, STAGE_A(t + 1, 0), READ_A(0, 1),              VMN);  // r1
    REGION(1, 0, STAGE_B(t + 2, 0), READ_B(0, 1),              VMN);  // r2
    REGION(1, 1, STAGE_A(t + 2, 1), READ_A(0, 0),              VM4);  // r3
    REGION(0, 1, STAGE_B(t + 2, 1), { READ_A(1, 0) READ_B(1, 0) }, VMN); // r4
    REGION(0, 0, STAGE_A(t + 2, 0), READ_A(1, 1),              VMN);  // r5
    REGION(1, 0, STAGE_B(t + 3, 0), READ_B(1, 1),              VMN);  // r6
    REGION(1, 1, STAGE_A(t + 3, 1), READ_A(1, 0),              VM4);  // r7
    REGION(0, 1, STAGE_B(t + 3, 1), { READ_A(0, 0) READ_B(0, 0) }, VMN); // r8
  }
  // peel (tiles NT-2 [buf0], NT-1 [buf1]): only A0[NT-1] remains to stage.
  REGION(0, 0, STAGE_A(NT - 1, 0), READ_A(0, 1),               VMN);  // q1
  REGION(1, 0, NOSTAGE,            READ_B(0, 1),               VMN);  // q2
  REGION(1, 1, NOSTAGE,            READ_A(0, 0),               VM0);  // q3
  REGION(0, 1, NOSTAGE,            { READ_A(1, 0) READ_B(1, 0) }, VMN); // q4
  REGION(0, 0, NOSTAGE,            READ_A(1, 1),               VMN);  // q5
  REGION(1, 0, NOSTAGE,            READ_B(1, 1),               VMN);  // q6
  REGION(1, 1, NOSTAGE,            READ_A(1, 0),               VMN);  // q7
  REGION(0, 1, NOSTAGE,            NOSTAGE,                    VMN);  // q8

  // epilogue: C/D layout col = lane&15, row = (lane>>4)*4 + r
  #pragma unroll
  for (int qc = 0; qc < 2; qc++) {
    #pragma unroll
    for (int ni = 0; ni < 4; ni++) {
      const int col = bn + qc * 128 + wcol + ni * 16 + lrow;
      const float bv = bias[col];
      #pragma unroll
      for (int qr = 0; qr < 2; qr++) {
        #pragma unroll
        for (int mi = 0; mi < 2; mi++) {
          #pragma unroll
          for (int r = 0; r < 4; r++) {
            const int row = bm + qr * 128 + wrow + mi * 16 + quad * 4 + r;
            const float val = acc[qr][qc][mi][ni][r] + bv;
            if (OUT_F32)
              ((float*)Cv)[(long)row * N + col] = val;
            else
              ((u16*)Cv)[(long)row * N + col] = f2bf(val);
          }
        }
      }
    }
  }
}

// ---------------------------------------------------------------------------
// Per-token attention across the 16 heads. One wave per token. (unchanged)
// ---------------------------------------------------------------------------
__global__ __launch_bounds__(256) void attn_local(u16* __restrict__ qkv) {
  __shared__ float p_s[4][16][16];
  const int tid  = threadIdx.x;
  const int wave = tid >> 6;
  const int lane = tid & 63;
  const int t    = blockIdx.x * 4 + wave;
  u16* row = qkv + (long)t * THREE_D;
  const int lrow = lane & 15;
  const int quad = lane >> 4;
  const int kq   = quad * 8;

  short8 a0 = *reinterpret_cast<const short8*>(row + lrow * 192 + kq);
  short8 a1 = *reinterpret_cast<const short8*>(row + lrow * 192 + 32 + kq);
  short8 b0 = *reinterpret_cast<const short8*>(row + lrow * 192 + 64 + kq);
  short8 b1 = *reinterpret_cast<const short8*>(row + lrow * 192 + 96 + kq);
  f32x4 s = {0.f, 0.f, 0.f, 0.f};
  s = __builtin_amdgcn_mfma_f32_16x16x32_bf16(a0, b0, s, 0, 0, 0);
  s = __builtin_amdgcn_mfma_f32_16x16x32_bf16(a1, b1, s, 0, 0, 0);

  const float scale = 0.125f;  // 1/sqrt(64)
  float p[4];
  #pragma unroll
  for (int r = 0; r < 4; r++) {
    float x = s[r] * scale;
    float m = x;
    #pragma unroll
    for (int mask = 1; mask < 16; mask <<= 1) m = fmaxf(m, __shfl_xor(m, mask));
    float e = __expf(x - m);
    float l = e;
    #pragma unroll
    for (int mask = 1; mask < 16; mask <<= 1) l += __shfl_xor(l, mask);
    p[r] = e / l;
  }
  #pragma unroll
  for (int r = 0; r < 4; r++) p_s[wave][quad * 4 + r][lrow] = p[r];
  __syncthreads();

  float o[16];
  #pragma unroll
  for (int i = 0; i < 16; i++) o[i] = 0.f;
  #pragma unroll
  for (int j = 0; j < 16; j++) {
    float vj = bf2f(row[j * 192 + 128 + lane]);
    #pragma unroll
    for (int i = 0; i < 16; i++) o[i] += p_s[wave][i][j] * vj;
  }
  #pragma unroll
  for (int i = 0; i < 16; i++)
    row[i * 192 + lane] = f2bf(o[i]);
}

// ---------------------------------------------------------------------------
extern "C" void kernel_launch(void* const* d_in, const int* in_sizes, int n_in,
                              void* d_out, int out_size, void* d_ws, size_t ws_size,
                              hipStream_t stream) {
  const float* x     = (const float*)d_in[0];  // (T, 1024) f32
  const float* W_qkv = (const float*)d_in[1];  // (1024, 3072) f32
  const float* b_qkv = (const float*)d_in[2];  // (3072) f32
  const float* W_out = (const float*)d_in[3];  // (1024, 1024) f32
  const float* b_out = (const float*)d_in[4];  // (1024) f32
  float* out = (float*)d_out;                  // (T, 1024) f32

  char* ws = (char*)d_ws;
  u16* qkv   = (u16*)ws;  ws += (size_t)TOKENS * THREE_D * 2;   // 192 MiB
  u16* x_bf  = (u16*)ws;  ws += (size_t)TOKENS * DMODEL * 2;    //  64 MiB
  u16* wqkvT = (u16*)ws;  ws += (size_t)THREE_D * DMODEL * 2;   //   6 MiB
  u16* woutT = (u16*)ws;                                        //   2 MiB

  dim3 tb(256);
  dim3 gtb(512);
  convert_f32_bf16<<<dim3((TOKENS * DMODEL) / 1024), tb, 0, stream>>>(
      x, x_bf, (long)TOKENS * DMODEL);
  transpose_convert<<<dim3(THREE_D / 32, DMODEL / 32), tb, 0, stream>>>(W_qkv, wqkvT, DMODEL, THREE_D);
  transpose_convert<<<dim3(DMODEL / 32, DMODEL / 32), tb, 0, stream>>>(W_out, woutT, DMODEL, DMODEL);
  // GEMM1: qkv = x @ W_qkv + b_qkv   (bf16 out, identity A-map)  grid=1536
  gemm_bt_bias<false><<<dim3((TOKENS / BM) * (THREE_D / BN)), gtb, 0, stream>>>(
      x_bf, wqkvT, b_qkv, qkv, TOKENS, THREE_D, DMODEL, (long)DMODEL, 64);
  // attention (in place: output -> q-slots of qkv)
  attn_local<<<dim3(TOKENS / 4), tb, 0, stream>>>(qkv);
  // GEMM2: out = vals @ W_out + b_out  (f32 out; A = q-slots)  grid=512
  gemm_bt_bias<true><<<dim3((TOKENS / BM) * (DMODEL / BN)), gtb, 0, stream>>>(
      qkv, woutT, b_out, out, TOKENS, DMODEL, DMODEL, (long)THREE_D, 192);
}

// Round 4
// 610.203 us; speedup vs baseline: 1.0117x; 1.0117x over previous
//
#include <hip/hip_runtime.h>
#include <hip/hip_bf16.h>

// Problem constants (B=8, S=4096, D=1024, H=16, hd=64). All I/O is FLOAT32.
#define TOKENS   32768
#define DMODEL   1024
#define THREE_D  3072

using u16 = unsigned short;
typedef __attribute__((ext_vector_type(8))) short short8;  // 8 bf16 = 4 VGPRs
typedef __attribute__((ext_vector_type(4))) float f32x4;

__device__ __forceinline__ float bf2f(u16 u) {
  union { unsigned int i; float f; } v; v.i = ((unsigned int)u) << 16; return v.f;
}
__device__ __forceinline__ u16 f2bf(float f) {
  __hip_bfloat16 h = __float2bfloat16(f);   // RNE
  return *reinterpret_cast<u16*>(&h);
}

// async global->LDS, 16B per lane; LDS dest = wave-uniform base + lane*16
__device__ __forceinline__ void gload_lds16(const u16* g, u16* l) {
  __builtin_amdgcn_global_load_lds((const __attribute__((address_space(1))) void*)g,
                                   (__attribute__((address_space(3))) void*)l,
                                   16, 0, 0);
}

// ---------------------------------------------------------------------------
// f32 -> bf16 elementwise convert (n divisible by 1024)
// ---------------------------------------------------------------------------
__global__ __launch_bounds__(256) void convert_f32_bf16(const float* __restrict__ in,
                                                        u16* __restrict__ out, long n) {
  long i = ((long)blockIdx.x * 256 + threadIdx.x) * 4;
  if (i >= n) return;
  float4 v = *reinterpret_cast<const float4*>(in + i);
  ushort4 o;
  o.x = f2bf(v.x); o.y = f2bf(v.y); o.z = f2bf(v.z); o.w = f2bf(v.w);
  *reinterpret_cast<ushort4*>(out + i) = o;
}

// ---------------------------------------------------------------------------
// f32 in (R x C) -> bf16 out (C x R) transpose+convert. R, C multiples of 32.
// ---------------------------------------------------------------------------
__global__ __launch_bounds__(256) void transpose_convert(const float* __restrict__ in,
                                                         u16* __restrict__ out,
                                                         int R, int C) {
  __shared__ u16 tile[32][33];
  const int bc = blockIdx.x * 32;
  const int br = blockIdx.y * 32;
  const int tx = threadIdx.x & 31;
  const int ty = threadIdx.x >> 5;
  #pragma unroll
  for (int i = 0; i < 32; i += 8)
    tile[ty + i][tx] = f2bf(in[(long)(br + ty + i) * C + bc + tx]);
  __syncthreads();
  #pragma unroll
  for (int i = 0; i < 32; i += 8)
    out[(long)(bc + ty + i) * R + br + tx] = tile[tx][ty + i];
}

// ---------------------------------------------------------------------------
// C(M,N) = A(M,K) @ BT(N,K)^T + bias(N).  A,BT bf16; bias f32; MFMA f32 acc.
// 256x256 tile, 8 waves (512 thr), BK=64, 8-phase counted-vmcnt schedule.
// (round-2 verified variant -- frozen this round)
// ---------------------------------------------------------------------------
#define BM 256
#define BN 256
#define BK 64

#define VM6 asm volatile("s_waitcnt vmcnt(6)" ::: "memory")
#define VM0 asm volatile("s_waitcnt vmcnt(0)" ::: "memory")
#define VMN ((void)0)
#define NOSTAGE ((void)0)

// stage one 128-row half (H) of A or B for K-tile T into buffer (T&1)
#define STAGE_A(T, H)                                                          \
  { _Pragma("unroll") for (int j_ = 0; j_ < 2; j_++) {                         \
      const int lr_ = (H) * 128 + (wave * 2 + j_) * 8;                         \
      gload_lds16(A + (long)(bm + lr_ + sr) * a_stride + (long)(T) * a_grp + scol, \
                  &As[(T) & 1][lr_ * BK]);                                     \
  } }
#define STAGE_B(T, H)                                                          \
  { _Pragma("unroll") for (int j_ = 0; j_ < 2; j_++) {                         \
      const int lr_ = (H) * 128 + (wave * 2 + j_) * 8;                         \
      gload_lds16(BT + (long)(bn + lr_ + sr) * K + (T) * BK + scol,            \
                  &Bs[(T) & 1][lr_ * BK]);                                     \
  } }

// one phase: quadrant (QR,QC) of the buffer-BUF K-tile.
// RDA/RDB: refresh the A/B register fragments (else reuse previous phase's).
#define PHASE(BUF, QR, QC, RDA, RDB, STAGE, VMW)                               \
  {                                                                            \
    if (RDA) {                                                                 \
      _Pragma("unroll") for (int mi = 0; mi < 2; mi++)                         \
        _Pragma("unroll") for (int kh = 0; kh < 2; kh++)                       \
          a[mi][kh] = *reinterpret_cast<const short8*>(                        \
              &As[BUF][((QR) * 128 + wrow + mi * 16 + lrow) * BK +             \
                       (((kh * 4 + quad) ^ xs) * 8)]);                         \
    }                                                                          \
    if (RDB) {                                                                 \
      _Pragma("unroll") for (int ni = 0; ni < 4; ni++)                         \
        _Pragma("unroll") for (int kh = 0; kh < 2; kh++)                       \
          b[ni][kh] = *reinterpret_cast<const short8*>(                        \
              &Bs[BUF][((QC) * 128 + wcol + ni * 16 + lrow) * BK +             \
                       (((kh * 4 + quad) ^ xs) * 8)]);                         \
    }                                                                          \
    STAGE;                                                                     \
    VMW;                                                                       \
    __builtin_amdgcn_s_barrier();                                              \
    asm volatile("s_waitcnt lgkmcnt(0)" ::: "memory");                         \
    __builtin_amdgcn_sched_barrier(0);                                         \
    __builtin_amdgcn_s_setprio(1);                                             \
    _Pragma("unroll") for (int mi = 0; mi < 2; mi++)                           \
      _Pragma("unroll") for (int ni = 0; ni < 4; ni++) {                       \
        acc[QR][QC][mi][ni] = __builtin_amdgcn_mfma_f32_16x16x32_bf16(         \
            a[mi][0], b[ni][0], acc[QR][QC][mi][ni], 0, 0, 0);                 \
        acc[QR][QC][mi][ni] = __builtin_amdgcn_mfma_f32_16x16x32_bf16(         \
            a[mi][1], b[ni][1], acc[QR][QC][mi][ni], 0, 0, 0);                 \
      }                                                                        \
    __builtin_amdgcn_s_setprio(0);                                             \
    __builtin_amdgcn_s_barrier();                                              \
    __builtin_amdgcn_sched_barrier(0);                                         \
  }

template <bool OUT_F32>
__global__ __launch_bounds__(512, 2) void gemm_bt_bias(
    const u16* __restrict__ A, const u16* __restrict__ BT,
    const float* __restrict__ bias, void* __restrict__ Cv,
    int M, int N, int K, long a_stride, int a_grp) {
  __shared__ alignas(16) u16 As[2][BM * BK];  // 64 KB
  __shared__ alignas(16) u16 Bs[2][BN * BK];  // 64 KB
  (void)M;

  // XCD-aware bijective swizzle (gridDim.x % 8 == 0 for our shapes)
  const int cpx = gridDim.x >> 3;
  const int wg  = ((int)blockIdx.x & 7) * cpx + ((int)blockIdx.x >> 3);
  const int tiles_n = N / BN;
  const int bm = (wg / tiles_n) * BM;
  const int bn = (wg % tiles_n) * BN;

  const int tid  = threadIdx.x;
  const int wave = tid >> 6;           // 0..7
  const int lane = tid & 63;
  const int wrow = (wave & 3) * 32;    // row slice within a 128-row quadrant
  const int wcol = (wave >> 2) * 64;   // col slice within a 128-col quadrant
  const int lrow = lane & 15;
  const int quad = lane >> 4;
  const int xs   = lrow & 7;

  // staging lane decomposition
  const int sr     = lane >> 3;              // row within 8-row group
  const int schunk = (lane & 7) ^ sr;        // GLOBAL 16B chunk this lane loads
  const int scol   = schunk * 8;

  const int NT = K / BK;   // even, >= 4

  f32x4 acc[2][2][2][4];
  #pragma unroll
  for (int i = 0; i < 2; i++)
    #pragma unroll
    for (int j = 0; j < 2; j++)
      #pragma unroll
      for (int m = 0; m < 2; m++)
        #pragma unroll
        for (int n = 0; n < 4; n++) acc[i][j][m][n] = (f32x4){0.f, 0.f, 0.f, 0.f};

  // prologue: tile0 fully (8 loads) + tile1's B0,A1,B1 (6 loads).
  STAGE_A(0, 0); STAGE_B(0, 0); STAGE_A(0, 1); STAGE_B(0, 1);
  STAGE_B(1, 0); STAGE_A(1, 1); STAGE_B(1, 1);
  VM6;
  __builtin_amdgcn_s_barrier();

  short8 a[2][2];
  short8 b[4][2];
  #pragma unroll 1
  for (int t = 0; t + 3 < NT; t += 2) {
    PHASE(0, 0, 0, 1, 1, STAGE_A(t + 1, 0), VMN);   // p1
    PHASE(0, 1, 0, 1, 0, STAGE_B(t + 2, 0), VMN);   // p2
    PHASE(0, 1, 1, 0, 1, STAGE_A(t + 2, 1), VMN);   // p3
    PHASE(0, 0, 1, 1, 0, STAGE_B(t + 2, 1), VM6);   // p4: tile t+1 covered
    PHASE(1, 0, 0, 1, 1, STAGE_A(t + 2, 0), VMN);   // p5
    PHASE(1, 1, 0, 1, 0, STAGE_B(t + 3, 0), VMN);   // p6
    PHASE(1, 1, 1, 0, 1, STAGE_A(t + 3, 1), VMN);   // p7
    PHASE(1, 0, 1, 1, 0, STAGE_B(t + 3, 1), VM6);   // p8: tile t+2 covered
  }
  // peeled last pair (t = NT-2, NT-1): only A0[NT-1] remains to stage.
  PHASE(0, 0, 0, 1, 1, STAGE_A(NT - 1, 0), VMN);
  PHASE(0, 1, 0, 1, 0, NOSTAGE, VMN);
  PHASE(0, 1, 1, 0, 1, NOSTAGE, VMN);
  PHASE(0, 0, 1, 1, 0, NOSTAGE, VM0);               // tail drain (once)
  PHASE(1, 0, 0, 1, 1, NOSTAGE, VMN);
  PHASE(1, 1, 0, 1, 0, NOSTAGE, VMN);
  PHASE(1, 1, 1, 0, 1, NOSTAGE, VMN);
  PHASE(1, 0, 1, 1, 0, NOSTAGE, VMN);

  // epilogue: C/D layout col = lane&15, row = (lane>>4)*4 + r
  #pragma unroll
  for (int qc = 0; qc < 2; qc++) {
    #pragma unroll
    for (int ni = 0; ni < 4; ni++) {
      const int col = bn + qc * 128 + wcol + ni * 16 + lrow;
      const float bv = bias[col];
      #pragma unroll
      for (int qr = 0; qr < 2; qr++) {
        #pragma unroll
        for (int mi = 0; mi < 2; mi++) {
          #pragma unroll
          for (int r = 0; r < 4; r++) {
            const int row = bm + qr * 128 + wrow + mi * 16 + quad * 4 + r;
            const float val = acc[qr][qc][mi][ni][r] + bv;
            if (OUT_F32)
              ((float*)Cv)[(long)row * N + col] = val;
            else
              ((u16*)Cv)[(long)row * N + col] = f2bf(val);
          }
        }
      }
    }
  }
}

// ---------------------------------------------------------------------------
// Per-token attention across the 16 heads. One wave per token.
// scores(16x16) via 2 MFMAs straight from global; softmax via intra-quad
// shuffles; PV via MFMA:  O = P @ V  with A-frag = P (i=lane&15 row,
// k=quad*8+jj), B-frag = V gathered per-lane.  K=32 vs j-range 16 gives a
// free double-bf16 P: k 0..15 = P_hi paired with V, k 16..31 = P_lo paired
// with the SAME V rows (duplicate-j gather) -> O = (P_hi + P_lo) @ V.
// Output written IN PLACE into the q-slots (q consumed; v disjoint).
// ---------------------------------------------------------------------------
__global__ __launch_bounds__(256) void attn_local(u16* __restrict__ qkv) {
  // [wave][i=head 0..15][k: 0..15 P_hi, 16..31 P_lo, 32..39 pad] bf16
  // stride 40 u16 = 80 B: keeps every row slice 16B-aligned, spreads banks.
  __shared__ alignas(16) u16 p_su[4][16][40];
  const int tid  = threadIdx.x;
  const int wave = tid >> 6;
  const int lane = tid & 63;
  const int t    = blockIdx.x * 4 + wave;
  u16* row = qkv + (long)t * THREE_D;
  const int lrow = lane & 15;
  const int quad = lane >> 4;
  const int kq   = quad * 8;

  // A-frag: q[m=lrow][d], B-frag: k[n=lrow][d]  (d = quad*8+j, two 32-chunks)
  short8 a0 = *reinterpret_cast<const short8*>(row + lrow * 192 + kq);
  short8 a1 = *reinterpret_cast<const short8*>(row + lrow * 192 + 32 + kq);
  short8 b0 = *reinterpret_cast<const short8*>(row + lrow * 192 + 64 + kq);
  short8 b1 = *reinterpret_cast<const short8*>(row + lrow * 192 + 96 + kq);
  f32x4 s = {0.f, 0.f, 0.f, 0.f};
  s = __builtin_amdgcn_mfma_f32_16x16x32_bf16(a0, b0, s, 0, 0, 0);
  s = __builtin_amdgcn_mfma_f32_16x16x32_bf16(a1, b1, s, 0, 0, 0);

  const float scale = 0.125f;  // 1/sqrt(64)
  #pragma unroll
  for (int r = 0; r < 4; r++) {
    // score row i = quad*4+r lives in the 16 lanes of this quad (col = lane&15)
    float x = s[r] * scale;
    float m = x;
    #pragma unroll
    for (int mask = 1; mask < 16; mask <<= 1) m = fmaxf(m, __shfl_xor(m, mask));
    float e = __expf(x - m);
    float l = e;
    #pragma unroll
    for (int mask = 1; mask < 16; mask <<= 1) l += __shfl_xor(l, mask);
    float p = e / l;
    u16 hi = f2bf(p);
    u16 lo = f2bf(p - bf2f(hi));
    p_su[wave][quad * 4 + r][lrow]      = hi;   // P_hi[i][j=lrow]
    p_su[wave][quad * 4 + r][16 + lrow] = lo;   // P_lo[i][j=lrow]
  }
  __syncthreads();

  // A-frag for PV: lane holds P'[i=lrow][k=kq..kq+7]  (one aligned b128)
  short8 pa = *reinterpret_cast<const short8*>(&p_su[wave][lrow][kq]);

  // B-frags: lane holds V'[k=kq+jj][n=lrow] = V[(quad&1)*8+jj][c*16+lrow]
  const u16* vbase = row + 128 + ((quad & 1) * 8) * 192 + lrow;
  short8 vb[4];
  #pragma unroll
  for (int c = 0; c < 4; c++) {
    #pragma unroll
    for (int jj = 0; jj < 8; jj++)
      vb[c][jj] = (short)vbase[jj * 192 + c * 16];
  }

  f32x4 o[4];
  #pragma unroll
  for (int c = 0; c < 4; c++) {
    o[c] = (f32x4){0.f, 0.f, 0.f, 0.f};
    o[c] = __builtin_amdgcn_mfma_f32_16x16x32_bf16(pa, vb[c], o[c], 0, 0, 0);
  }

  // in-place write into q-slots: head i = quad*4+r, dim d = c*16+lrow
  #pragma unroll
  for (int c = 0; c < 4; c++)
    #pragma unroll
    for (int r = 0; r < 4; r++)
      row[(quad * 4 + r) * 192 + c * 16 + lrow] = f2bf(o[c][r]);
}

// ---------------------------------------------------------------------------
extern "C" void kernel_launch(void* const* d_in, const int* in_sizes, int n_in,
                              void* d_out, int out_size, void* d_ws, size_t ws_size,
                              hipStream_t stream) {
  const float* x     = (const float*)d_in[0];  // (T, 1024) f32
  const float* W_qkv = (const float*)d_in[1];  // (1024, 3072) f32
  const float* b_qkv = (const float*)d_in[2];  // (3072) f32
  const float* W_out = (const float*)d_in[3];  // (1024, 1024) f32
  const float* b_out = (const float*)d_in[4];  // (1024) f32
  float* out = (float*)d_out;                  // (T, 1024) f32

  char* ws = (char*)d_ws;
  u16* qkv   = (u16*)ws;  ws += (size_t)TOKENS * THREE_D * 2;   // 192 MiB
  u16* x_bf  = (u16*)ws;  ws += (size_t)TOKENS * DMODEL * 2;    //  64 MiB
  u16* wqkvT = (u16*)ws;  ws += (size_t)THREE_D * DMODEL * 2;   //   6 MiB
  u16* woutT = (u16*)ws;                                        //   2 MiB

  dim3 tb(256);
  dim3 gtb(512);
  convert_f32_bf16<<<dim3((TOKENS * DMODEL) / 1024), tb, 0, stream>>>(
      x, x_bf, (long)TOKENS * DMODEL);
  transpose_convert<<<dim3(THREE_D / 32, DMODEL / 32), tb, 0, stream>>>(W_qkv, wqkvT, DMODEL, THREE_D);
  transpose_convert<<<dim3(DMODEL / 32, DMODEL / 32), tb, 0, stream>>>(W_out, woutT, DMODEL, DMODEL);
  // GEMM1: qkv = x @ W_qkv + b_qkv   (bf16 out, identity A-map)  grid=1536
  gemm_bt_bias<false><<<dim3((TOKENS / BM) * (THREE_D / BN)), gtb, 0, stream>>>(
      x_bf, wqkvT, b_qkv, qkv, TOKENS, THREE_D, DMODEL, (long)DMODEL, 64);
  // attention (in place: output -> q-slots of qkv)
  attn_local<<<dim3(TOKENS / 4), tb, 0, stream>>>(qkv);
  // GEMM2: out = vals @ W_out + b_out  (f32 out; A = q-slots)  grid=512
  gemm_bt_bias<true><<<dim3((TOKENS / BM) * (DMODEL / BN)), gtb, 0, stream>>>(
      qkv, woutT, b_out, out, TOKENS, DMODEL, DMODEL, (long)THREE_D, 192);
}

// Round 5
// 580.083 us; speedup vs baseline: 1.0643x; 1.0519x over previous
//
#include <hip/hip_runtime.h>
#include <hip/hip_bf16.h>

// Problem constants (B=8, S=4096, D=1024, H=16, hd=64). All I/O is FLOAT32.
#define TOKENS   32768
#define DMODEL   1024
#define THREE_D  3072

using u16 = unsigned short;
typedef __attribute__((ext_vector_type(8))) short short8;   // 8 bf16 = 4 VGPRs
typedef __attribute__((ext_vector_type(4))) float f32x4;
typedef __attribute__((ext_vector_type(16))) float f32x16;  // 32x32 MFMA acc

__device__ __forceinline__ float bf2f(u16 u) {
  union { unsigned int i; float f; } v; v.i = ((unsigned int)u) << 16; return v.f;
}
__device__ __forceinline__ u16 f2bf(float f) {
  __hip_bfloat16 h = __float2bfloat16(f);   // RNE
  return *reinterpret_cast<u16*>(&h);
}

// async global->LDS, 16B per lane; LDS dest = wave-uniform base + lane*16
__device__ __forceinline__ void gload_lds16(const u16* g, u16* l) {
  __builtin_amdgcn_global_load_lds((const __attribute__((address_space(1))) void*)g,
                                   (__attribute__((address_space(3))) void*)l,
                                   16, 0, 0);
}

// ---------------------------------------------------------------------------
// f32 -> bf16 elementwise convert (n divisible by 1024)
// ---------------------------------------------------------------------------
__global__ __launch_bounds__(256) void convert_f32_bf16(const float* __restrict__ in,
                                                        u16* __restrict__ out, long n) {
  long i = ((long)blockIdx.x * 256 + threadIdx.x) * 4;
  if (i >= n) return;
  float4 v = *reinterpret_cast<const float4*>(in + i);
  ushort4 o;
  o.x = f2bf(v.x); o.y = f2bf(v.y); o.z = f2bf(v.z); o.w = f2bf(v.w);
  *reinterpret_cast<ushort4*>(out + i) = o;
}

// ---------------------------------------------------------------------------
// f32 in (R x C) -> bf16 out (C x R) transpose+convert. R, C multiples of 32.
// ---------------------------------------------------------------------------
__global__ __launch_bounds__(256) void transpose_convert(const float* __restrict__ in,
                                                         u16* __restrict__ out,
                                                         int R, int C) {
  __shared__ u16 tile[32][33];
  const int bc = blockIdx.x * 32;
  const int br = blockIdx.y * 32;
  const int tx = threadIdx.x & 31;
  const int ty = threadIdx.x >> 5;
  #pragma unroll
  for (int i = 0; i < 32; i += 8)
    tile[ty + i][tx] = f2bf(in[(long)(br + ty + i) * C + bc + tx]);
  __syncthreads();
  #pragma unroll
  for (int i = 0; i < 32; i += 8)
    out[(long)(bc + ty + i) * R + br + tx] = tile[tx][ty + i];
}

// ---------------------------------------------------------------------------
// C(M,N) = A(M,K) @ BT(N,K)^T + bias(N).  A,BT bf16; bias f32; MFMA f32 acc.
// 256x256 tile, 8 waves (512 thr), BK=64, mfma_f32_32x32x16_bf16.
//
// NEW STRUCTURE (counted-lgkm read-ahead):
//   phase = ONE k-step (K=16) over the full per-wave 128x64 tile:
//     8 MFMA(32x32x16), 6 ds_read_b128.
//   Each phase issues the NEXT phase's fragments into the ALTERNATE register
//   set, then waits s_waitcnt lgkmcnt(6) (drains the previous set, lets the
//   just-issued 6 float) -> LDS service of reads(p+1) overlaps the MFMA
//   crunch of phase p.  One s_barrier per phase.
//
// Per K-tile t (buf R=t&1; stages tile t+1 into buf R^1):
//   ks0: BAR; rd(ks1,R); STAGE A-halves[t+1]; LGKM6; MMA(set0)
//   ks1: BAR; rd(ks2,R); STAGE B-halves[t+1]; LGKM6; MMA(set1)
//   ks2: BAR; rd(ks3,R);                      LGKM6; MMA(set0); VM0
//   ks3: BAR; rd(t+1.ks0, R^1);               LGKM6; MMA(set1)
// Hazards: stage target buf R^1 last read at tile t-1 ks2 (>=2 barriers
// earlier); VM0 sits AFTER ks2's MFMA (stall overlaps crunch; loads have
// ~1.5 phases of HBM lead); ks3-top barrier makes staged data visible before
// the read-ahead into buf R^1.  vmcnt exact (no other vmem in loop).
//
// Fragments (32x32x16): A row = lane&31, k = (lane>>5)*8+j; same for BT.
// C/D: col = lane&31, row = (r&3) + 8*(r>>2) + 4*(lane>>5), r = 0..15.
// Wave map: wm = (wave>>2)*128 (A rows), wn = (wave&3)*64 (B cols); per wave
// 4 M-frags x 2 N-frags of 32x32 -> acc 8 x f32x16 = 128 AGPR.
//
// XOR chunk swizzle (conflict-free in 16-lane subgroups): staging lane L
// covers row base+(L>>3), phys 16B chunk (L&7), loading GLOBAL chunk
// (L&7)^(L>>3); reads fetch logical chunk c of row r at phys c^(r&7).
//
// A read through column remap: logical col c -> row*a_stride + (c>>6)*a_grp
// + (c&63).  Identity: a_stride=K, a_grp=64.  M%256==0, N%256==0,
// K%128==0 (NT even, >= 4).
// ---------------------------------------------------------------------------
#define BM 256
#define BN 256
#define BK 64

#define LGKM6 { asm volatile("s_waitcnt lgkmcnt(6)" ::: "memory"); \
                __builtin_amdgcn_sched_barrier(0); }
#define LGKM0 { asm volatile("s_waitcnt lgkmcnt(0)" ::: "memory"); \
                __builtin_amdgcn_sched_barrier(0); }
#define VMW0  asm volatile("s_waitcnt vmcnt(0)" ::: "memory")
#define BARR  { __builtin_amdgcn_sched_barrier(0); __builtin_amdgcn_s_barrier(); \
                __builtin_amdgcn_sched_barrier(0); }

// stage one 128-row half (H) of A or B for K-tile T into buffer (T&1): 2 loads
#define STAGE_A(T, H)                                                          \
  { _Pragma("unroll") for (int j_ = 0; j_ < 2; j_++) {                         \
      const int lr_ = (H) * 128 + (wave * 2 + j_) * 8;                         \
      gload_lds16(A + (long)(bm + lr_ + sr) * a_stride + (long)(T) * a_grp + scol, \
                  &As[(T) & 1][lr_ * BK]);                                     \
  } }
#define STAGE_B(T, H)                                                          \
  { _Pragma("unroll") for (int j_ = 0; j_ < 2; j_++) {                         \
      const int lr_ = (H) * 128 + (wave * 2 + j_) * 8;                         \
      gload_lds16(BT + (long)(bn + lr_ + sr) * K + (T) * BK + scol,            \
                  &Bs[(T) & 1][lr_ * BK]);                                     \
  } }

// fragment reads for k-step KS of buffer BUF into register set SET (6 b128)
#define READS(SET, BUF, KS)                                                    \
  { _Pragma("unroll") for (int f_ = 0; f_ < 4; f_++)                           \
      a[SET][f_] = *reinterpret_cast<const short8*>(                           \
          &As[BUF][(wm + f_ * 32 + l31) * BK + ((((KS) * 2 + kh) ^ xr) * 8)]); \
    _Pragma("unroll") for (int g_ = 0; g_ < 2; g_++)                           \
      b[SET][g_] = *reinterpret_cast<const short8*>(                           \
          &Bs[BUF][(wn + g_ * 32 + l31) * BK + ((((KS) * 2 + kh) ^ xr) * 8)]); }

// 8 independent MFMAs (full wave tile, one k-step) on register set SET
#define MMA(SET)                                                               \
  { __builtin_amdgcn_s_setprio(1);                                             \
    _Pragma("unroll") for (int mf_ = 0; mf_ < 4; mf_++)                        \
      _Pragma("unroll") for (int nf_ = 0; nf_ < 2; nf_++)                      \
        acc[mf_][nf_] = __builtin_amdgcn_mfma_f32_32x32x16_bf16(               \
            a[SET][mf_], b[SET][nf_], acc[mf_][nf_], 0, 0, 0);                 \
    __builtin_amdgcn_s_setprio(0); }

template <bool OUT_F32>
__global__ __launch_bounds__(512, 2) void gemm_bt_bias(
    const u16* __restrict__ A, const u16* __restrict__ BT,
    const float* __restrict__ bias, void* __restrict__ Cv,
    int M, int N, int K, long a_stride, int a_grp) {
  __shared__ alignas(16) u16 As[2][BM * BK];  // 64 KB
  __shared__ alignas(16) u16 Bs[2][BN * BK];  // 64 KB
  (void)M;

  // XCD-aware bijective swizzle (gridDim.x % 8 == 0 for our shapes)
  const int cpx = gridDim.x >> 3;
  const int wg  = ((int)blockIdx.x & 7) * cpx + ((int)blockIdx.x >> 3);
  const int tiles_n = N / BN;
  const int bm = (wg / tiles_n) * BM;
  const int bn = (wg % tiles_n) * BN;

  const int tid  = threadIdx.x;
  const int wave = tid >> 6;            // 0..7
  const int lane = tid & 63;
  const int wm   = (wave >> 2) * 128;   // A-row base (2 M-waves)
  const int wn   = (wave & 3) * 64;     // B-col base (4 N-waves)
  const int l31  = lane & 31;
  const int kh   = lane >> 5;           // k-half within 16-step
  const int xr   = l31 & 7;             // swizzle row bits

  // staging lane decomposition
  const int sr     = lane >> 3;              // row within 8-row group
  const int schunk = (lane & 7) ^ sr;        // GLOBAL 16B chunk this lane loads
  const int scol   = schunk * 8;

  const int NT = K / BK;   // even, >= 4

  f32x16 acc[4][2];
  #pragma unroll
  for (int i = 0; i < 4; i++)
    #pragma unroll
    for (int j = 0; j < 2; j++)
      #pragma unroll
      for (int r = 0; r < 16; r++) acc[i][j][r] = 0.f;

  // prologue: stage tile0 fully, drain, sync, pre-read ks0 into set0.
  STAGE_A(0, 0); STAGE_A(0, 1); STAGE_B(0, 0); STAGE_B(0, 1);
  VMW0;
  __builtin_amdgcn_s_barrier();

  short8 a[2][4];
  short8 b[2][2];
  READS(0, 0, 0);

  #pragma unroll 1
  for (int t = 0; t + 2 < NT; t += 2) {
    // tile t (buf 0), stage tile t+1 -> buf 1
    BARR; READS(1, 0, 1); STAGE_A(t + 1, 0); STAGE_A(t + 1, 1); LGKM6; MMA(0);
    BARR; READS(0, 0, 2); STAGE_B(t + 1, 0); STAGE_B(t + 1, 1); LGKM6; MMA(1);
    BARR; READS(1, 0, 3);                                       LGKM6; MMA(0); VMW0;
    BARR; READS(0, 1, 0);                                       LGKM6; MMA(1);
    // tile t+1 (buf 1), stage tile t+2 -> buf 0
    BARR; READS(1, 1, 1); STAGE_A(t + 2, 0); STAGE_A(t + 2, 1); LGKM6; MMA(0);
    BARR; READS(0, 1, 2); STAGE_B(t + 2, 0); STAGE_B(t + 2, 1); LGKM6; MMA(1);
    BARR; READS(1, 1, 3);                                       LGKM6; MMA(0); VMW0;
    BARR; READS(0, 0, 0);                                       LGKM6; MMA(1);
  }
  // peel tile NT-2 (buf 0), stage tile NT-1 -> buf 1
  BARR; READS(1, 0, 1); STAGE_A(NT - 1, 0); STAGE_A(NT - 1, 1); LGKM6; MMA(0);
  BARR; READS(0, 0, 2); STAGE_B(NT - 1, 0); STAGE_B(NT - 1, 1); LGKM6; MMA(1);
  BARR; READS(1, 0, 3);                                         LGKM6; MMA(0); VMW0;
  BARR; READS(0, 1, 0);                                         LGKM6; MMA(1);
  // peel tile NT-1 (buf 1), no stage
  BARR; READS(1, 1, 1);                                         LGKM6; MMA(0);
  BARR; READS(0, 1, 2);                                         LGKM6; MMA(1);
  BARR; READS(1, 1, 3);                                         LGKM6; MMA(0);
  BARR;                                                         LGKM0; MMA(1);

  // epilogue: 32x32 C/D layout  col = lane&31, row = (r&3)+8*(r>>2)+4*kh
  #pragma unroll
  for (int nf = 0; nf < 2; nf++) {
    const int col = bn + wn + nf * 32 + l31;
    const float bv = bias[col];
    #pragma unroll
    for (int mf = 0; mf < 4; mf++) {
      #pragma unroll
      for (int r = 0; r < 16; r++) {
        const int row = bm + wm + mf * 32 + (r & 3) + 8 * (r >> 2) + 4 * kh;
        const float val = acc[mf][nf][r] + bv;
        if (OUT_F32)
          ((float*)Cv)[(long)row * N + col] = val;
        else
          ((u16*)Cv)[(long)row * N + col] = f2bf(val);
      }
    }
  }
}

// ---------------------------------------------------------------------------
// Per-token attention across the 16 heads. One wave per token.
// (round-2 verified variant: MFMA QK^T, shuffle softmax, LDS-broadcast PV)
// ---------------------------------------------------------------------------
__global__ __launch_bounds__(256) void attn_local(u16* __restrict__ qkv) {
  __shared__ float p_s[4][16][16];
  const int tid  = threadIdx.x;
  const int wave = tid >> 6;
  const int lane = tid & 63;
  const int t    = blockIdx.x * 4 + wave;
  u16* row = qkv + (long)t * THREE_D;
  const int lrow = lane & 15;
  const int quad = lane >> 4;
  const int kq   = quad * 8;

  short8 a0 = *reinterpret_cast<const short8*>(row + lrow * 192 + kq);
  short8 a1 = *reinterpret_cast<const short8*>(row + lrow * 192 + 32 + kq);
  short8 b0 = *reinterpret_cast<const short8*>(row + lrow * 192 + 64 + kq);
  short8 b1 = *reinterpret_cast<const short8*>(row + lrow * 192 + 96 + kq);
  f32x4 s = {0.f, 0.f, 0.f, 0.f};
  s = __builtin_amdgcn_mfma_f32_16x16x32_bf16(a0, b0, s, 0, 0, 0);
  s = __builtin_amdgcn_mfma_f32_16x16x32_bf16(a1, b1, s, 0, 0, 0);

  const float scale = 0.125f;  // 1/sqrt(64)
  float p[4];
  #pragma unroll
  for (int r = 0; r < 4; r++) {
    float x = s[r] * scale;
    float m = x;
    #pragma unroll
    for (int mask = 1; mask < 16; mask <<= 1) m = fmaxf(m, __shfl_xor(m, mask));
    float e = __expf(x - m);
    float l = e;
    #pragma unroll
    for (int mask = 1; mask < 16; mask <<= 1) l += __shfl_xor(l, mask);
    p[r] = e / l;
  }
  #pragma unroll
  for (int r = 0; r < 4; r++) p_s[wave][quad * 4 + r][lrow] = p[r];
  __syncthreads();

  float o[16];
  #pragma unroll
  for (int i = 0; i < 16; i++) o[i] = 0.f;
  #pragma unroll
  for (int j = 0; j < 16; j++) {
    float vj = bf2f(row[j * 192 + 128 + lane]);
    #pragma unroll
    for (int i = 0; i < 16; i++) o[i] += p_s[wave][i][j] * vj;
  }
  #pragma unroll
  for (int i = 0; i < 16; i++)
    row[i * 192 + lane] = f2bf(o[i]);
}

// ---------------------------------------------------------------------------
extern "C" void kernel_launch(void* const* d_in, const int* in_sizes, int n_in,
                              void* d_out, int out_size, void* d_ws, size_t ws_size,
                              hipStream_t stream) {
  const float* x     = (const float*)d_in[0];  // (T, 1024) f32
  const float* W_qkv = (const float*)d_in[1];  // (1024, 3072) f32
  const float* b_qkv = (const float*)d_in[2];  // (3072) f32
  const float* W_out = (const float*)d_in[3];  // (1024, 1024) f32
  const float* b_out = (const float*)d_in[4];  // (1024) f32
  float* out = (float*)d_out;                  // (T, 1024) f32

  char* ws = (char*)d_ws;
  u16* qkv   = (u16*)ws;  ws += (size_t)TOKENS * THREE_D * 2;   // 192 MiB
  u16* x_bf  = (u16*)ws;  ws += (size_t)TOKENS * DMODEL * 2;    //  64 MiB
  u16* wqkvT = (u16*)ws;  ws += (size_t)THREE_D * DMODEL * 2;   //   6 MiB
  u16* woutT = (u16*)ws;                                        //   2 MiB

  dim3 tb(256);
  dim3 gtb(512);
  convert_f32_bf16<<<dim3((TOKENS * DMODEL) / 1024), tb, 0, stream>>>(
      x, x_bf, (long)TOKENS * DMODEL);
  transpose_convert<<<dim3(THREE_D / 32, DMODEL / 32), tb, 0, stream>>>(W_qkv, wqkvT, DMODEL, THREE_D);
  transpose_convert<<<dim3(DMODEL / 32, DMODEL / 32), tb, 0, stream>>>(W_out, woutT, DMODEL, DMODEL);
  // GEMM1: qkv = x @ W_qkv + b_qkv   (bf16 out, identity A-map)  grid=1536
  gemm_bt_bias<false><<<dim3((TOKENS / BM) * (THREE_D / BN)), gtb, 0, stream>>>(
      x_bf, wqkvT, b_qkv, qkv, TOKENS, THREE_D, DMODEL, (long)DMODEL, 64);
  // attention (in place: output -> q-slots of qkv)
  attn_local<<<dim3(TOKENS / 4), tb, 0, stream>>>(qkv);
  // GEMM2: out = vals @ W_out + b_out  (f32 out; A = q-slots)  grid=512
  gemm_bt_bias<true><<<dim3((TOKENS / BM) * (DMODEL / BN)), gtb, 0, stream>>>(
      qkv, woutT, b_out, out, TOKENS, DMODEL, DMODEL, (long)THREE_D, 192);
}